// Round 11
// baseline (73.923 us; speedup 1.0000x reference)
//
#include <hip/hip_runtime.h>

#define NPTS 16384
#define NNBR 32
#define CIN 16
#define COUT 16
#define NBASIS 16

// LDS f16 row stride 264 (528 B = 132 dw ≡ 4 mod 32): b128 reads alias 2-way (free).
#define WF_OS 264
#define ML_PS 264

// sqrt(10 * log2(e)) : exp(-10 d^2) == exp2(-(SCL*d)^2)
#define RSCL 3.7982825f

typedef _Float16 half8 __attribute__((ext_vector_type(8)));
typedef _Float16 half4 __attribute__((ext_vector_type(4)));
typedef unsigned short ushort8 __attribute__((ext_vector_type(8)));
typedef float floatx4 __attribute__((ext_vector_type(4)));

// ws layout (f16 units): [0, NPTS*16) xT16 [n][i] ; Wf16 [o][b*16+i] ;
// coords4 [n] = (x,y,z,0) f32. coords4 turns the 3-instruction divergent
// neighbor-coords read (192 VMEM transactions/wave) into ONE dwordx4
// (64 transactions/wave) -- the single largest transaction component.
#define WS_XT 0
#define WS_WF (NPTS * CIN)
#define WS_C4 (WS_WF + COUT * 256)   // halfword offset 266240 -> byte 532480 (16B-aligned)

// Prep: 256 blocks x 256 threads. Transpose input (R6-proven pattern),
// pack coords4, block 0 packs W.
__global__ __launch_bounds__(256) void prep_kernel(
        const float* __restrict__ input, const float* __restrict__ coords,
        const float* __restrict__ W, _Float16* __restrict__ ws) {
    const int p4 = threadIdx.x >> 2;          // 0..63 point within block
    const int c4i = threadIdx.x & 3;          // channel quad
    const int n = blockIdx.x * 64 + p4;
    half4 v;
    #pragma unroll
    for (int j = 0; j < 4; ++j)
        v[j] = (_Float16)input[(c4i * 4 + j) * NPTS + n];
    *(half4*)&ws[WS_XT + n * CIN + c4i * 4] = v;

    const int g = blockIdx.x * 256 + threadIdx.x;   // coords4 pack (coalesced)
    {
        float4 cv;
        cv.x = coords[3 * g + 0];
        cv.y = coords[3 * g + 1];
        cv.z = coords[3 * g + 2];
        cv.w = 0.0f;
        *(float4*)&((float*)&ws[WS_C4])[g * 4] = cv;
    }

    if (blockIdx.x == 0) {   // W -> [o][b*16+i] f16
        const int o = threadIdx.x >> 4, b = threadIdx.x & 15;
        _Float16 w[16];
        #pragma unroll
        for (int i = 0; i < CIN; ++i) w[i] = (_Float16)W[o * 256 + i * 16 + b];
        *(half8*)&ws[WS_WF + o * 256 + b * 16]     = *(half8*)&w[0];
        *(half8*)&ws[WS_WF + o * 256 + b * 16 + 8] = *(half8*)&w[8];
    }
}

// Conv: 2048 blocks x 256 = 8 points/block, 8 blocks/CU x 4 waves = 32
// waves/CU. R6 single-barrier body; ONLY change vs R6: coords via coords4
// (1 dwordx4 instead of 3 dwords -> per-wave VMEM transactions ~300 -> ~175).
__global__ __launch_bounds__(256, 8) void se3_conv_kernel(
        const _Float16* __restrict__ ws,
        const float* __restrict__ centers,   // (NBASIS,)
        const float* __restrict__ mask,      // (NPTS, NNBR) f32
        const int* __restrict__ neighbors,   // (NPTS, NNBR)
        float* __restrict__ out) {           // (COUT, NPTS)
    __shared__ _Float16 Wf[COUT * WF_OS];        // 8448 B
    __shared__ _Float16 Mld[8 * ML_PS];          // 4224 B
    __shared__ float    rs[8 * NNBR];            // 1024 B  (pre-scaled RSCL)
    __shared__ unsigned short nb16[8 * NNBR];    //  512 B
    __shared__ _Float16 mv16[8 * NNBR];          //  512 B

    const _Float16* xT16 = &ws[WS_XT];
    const float* c4 = (const float*)&ws[WS_C4];

    const int tid = threadIdx.x;
    const int t = tid & 15;          // lane role (i in B / o in C)
    const int quad = (tid >> 4) & 3; // k-chunk select
    const int wv = tid >> 6;         // wave 0..3
    const int nbase = blockIdx.x * 8;

    // ---- Phase A loads FIRST: one (pt,k) pair per thread.
    const int pt = tid >> 5;
    const int k = tid & 31;
    const int n = nbase + pt;
    const int nbr = neighbors[n * NNBR + k] & (NPTS - 1);
    const float m = mask[n * NNBR + k];
    const float4 nc = *(const float4*)&c4[n * 4];     // uniform per 32 lanes
    const float4 bc = *(const float4*)&c4[nbr * 4];   // ONE divergent dwordx4

    // ---- Stage Wf while phase-A loads are in flight (consumed in phase C).
    {
        const int o = tid >> 4, ch = tid & 15;
        const half8 w0 = *(const half8*)&ws[WS_WF + o * 256 + ch * 16];
        const half8 w1 = *(const half8*)&ws[WS_WF + o * 256 + ch * 16 + 8];
        *(half8*)&Wf[o * WF_OS + ch * 16]     = w0;
        *(half8*)&Wf[o * WF_OS + ch * 16 + 8] = w1;
    }

    // ---- Phase A compute + intra-wave LDS publish (lgkmcnt orders the
    // same-wave ds_write -> ds_read; no block barrier needed).
    {
        const float dx = bc.x - nc.x, dy = bc.y - nc.y, dz = bc.z - nc.z;
        rs[pt * NNBR + k] =
            sqrtf(dx * dx + dy * dy + dz * dz + 1e-12f) * RSCL;
        nb16[pt * NNBR + k] = (unsigned short)nbr;
        mv16[pt * NNBR + k] = (_Float16)m;
    }

    // ---- Phase B (pre-barrier): wave wv -> points 2wv, 2wv+1; one
    // mfma_16x16x32_f16 each.
    // A[m=i=t][k=8q+j] = x[nbr][t]*mask ; B[k][n=b=t] = exp2(-(rscl-c_t)^2)
    const float cs = centers[t] * RSCL;
    const int kb0 = (wv * 2 + 0) * NNBR + 8 * quad;  // group-broadcast LDS
    const int kb1 = (wv * 2 + 1) * NNBR + 8 * quad;
    const ushort8 nbv0 = *(const ushort8*)&nb16[kb0];
    const ushort8 nbv1 = *(const ushort8*)&nb16[kb1];
    const half8 mvv0 = *(const half8*)&mv16[kb0];
    const half8 mvv1 = *(const half8*)&mv16[kb1];
    const float4 r00 = *(const float4*)&rs[kb0];
    const float4 r01 = *(const float4*)&rs[kb0 + 4];
    const float4 r10 = *(const float4*)&rs[kb1];
    const float4 r11 = *(const float4*)&rs[kb1 + 4];

    // All 16 x-gathers issued before exp work (16-lane groups share a row:
    // 4 transactions/inst, 64/wave -- already minimal).
    half8 xh0, xh1;
    #pragma unroll
    for (int j = 0; j < 8; ++j) xh0[j] = xT16[(int)nbv0[j] * CIN + t];
    #pragma unroll
    for (int j = 0; j < 8; ++j) xh1[j] = xT16[(int)nbv1[j] * CIN + t];

    const float rj0[8] = {r00.x, r00.y, r00.z, r00.w, r01.x, r01.y, r01.z, r01.w};
    const float rj1[8] = {r10.x, r10.y, r10.z, r10.w, r11.x, r11.y, r11.z, r11.w};

    {   // q = 0
        half8 af, bf;
        #pragma unroll
        for (int j = 0; j < 8; ++j) {
            const float d = rj0[j] - cs;
            // v_exp_f32 is exp2 natively; negate folds into the src modifier.
            bf[j] = (_Float16)__builtin_amdgcn_exp2f(-(d * d));
        }
        af = xh0 * mvv0;                           // v_pk_mul_f16, no cvt chain
        floatx4 c = {0.0f, 0.0f, 0.0f, 0.0f};
        c = __builtin_amdgcn_mfma_f32_16x16x32_f16(af, bf, c, 0, 0, 0);
        _Float16 h[4];
        #pragma unroll
        for (int v = 0; v < 4; ++v) h[v] = (_Float16)c[v];
        // D[row=i=4quad+v][col=b=t] -> Mld[pq][t*16 + 4quad + v] (one b64)
        *(uint2*)&Mld[(wv * 2 + 0) * ML_PS + t * 16 + 4 * quad] = *(uint2*)h;
    }
    {   // q = 1
        half8 af, bf;
        #pragma unroll
        for (int j = 0; j < 8; ++j) {
            const float d = rj1[j] - cs;
            bf[j] = (_Float16)__builtin_amdgcn_exp2f(-(d * d));
        }
        af = xh1 * mvv1;
        floatx4 c = {0.0f, 0.0f, 0.0f, 0.0f};
        c = __builtin_amdgcn_mfma_f32_16x16x32_f16(af, bf, c, 0, 0, 0);
        _Float16 h[4];
        #pragma unroll
        for (int v = 0; v < 4; ++v) h[v] = (_Float16)c[v];
        *(uint2*)&Mld[(wv * 2 + 1) * ML_PS + t * 16 + 4 * quad] = *(uint2*)h;
    }

    __syncthreads();   // the ONLY barrier: {Wf, Mld} -> phase C

    // ---- Phase C (every wave, redundant): Out = W(16x256) * Mflat(256x8).
    // A[m=o=t][bi-chunk]; B[bi-chunk][n=pt=t] valid for t<8 (cols 8-15 zero).
    floatx4 acc = {0.0f, 0.0f, 0.0f, 0.0f};
    #pragma unroll
    for (int cch = 0; cch < 8; ++cch) {
        const int bi = cch * 32 + 8 * quad;
        const half8 a = *(const half8*)&Wf[t * WF_OS + bi];
        half8 b = {};
        if (t < 8) b = *(const half8*)&Mld[t * ML_PS + bi];
        acc = __builtin_amdgcn_mfma_f32_16x16x32_f16(a, b, acc, 0, 0, 0);
    }
    // D[row=o=4quad+v][col=pt=t]; wave wv stores cols 2wv, 2wv+1.
    if (t < 8 && wv == (t >> 1)) {
        #pragma unroll
        for (int v = 0; v < 4; ++v)
            out[(4 * quad + v) * NPTS + nbase + t] = acc[v];
    }
}

extern "C" void kernel_launch(void* const* d_in, const int* in_sizes, int n_in,
                              void* d_out, int out_size, void* d_ws, size_t ws_size,
                              hipStream_t stream) {
    const float* input   = (const float*)d_in[0];
    const float* coords  = (const float*)d_in[1];
    const float* W       = (const float*)d_in[2];
    const float* centers = (const float*)d_in[3];
    const float* mask    = (const float*)d_in[4];
    const int*   nbr     = (const int*)d_in[5];
    float* out = (float*)d_out;
    _Float16* ws = (_Float16*)d_ws;   // ~1 MB of the 256 MB workspace

    prep_kernel<<<NPTS / 64, 256, 0, stream>>>(input, coords, W, ws);
    se3_conv_kernel<<<NPTS / 8, 256, 0, stream>>>(ws, centers, mask, nbr, out);
}